// Round 1
// baseline (531.002 us; speedup 1.0000x reference)
//
#include <hip/hip_runtime.h>
#include <math.h>

// Problem sizes (fixed by the reference)
#define NB   2
#define CC   256
#define HH   64
#define WW   64
#define NH   8
#define DD   32
#define PQ   4096   // 64*64 queries per image
#define PKV  1024   // 32*32 kv per image
#define WIN  18     // max kv window extent per axis

#define NF (-INFINITY)

// res = dot(qarr[0..31], ptr[0..31]) with 4 partial sums (ILP)
#define DOT32(res, qarr, ptr)                                    \
  {                                                              \
    const float4* _r = reinterpret_cast<const float4*>(ptr);     \
    float _s0 = 0.f, _s1 = 0.f, _s2 = 0.f, _s3 = 0.f;            \
    _Pragma("unroll")                                            \
    for (int _t = 0; _t < 8; ++_t) {                             \
      const float4 _v = _r[_t];                                  \
      _s0 = fmaf(qarr[4 * _t + 0], _v.x, _s0);                   \
      _s1 = fmaf(qarr[4 * _t + 1], _v.y, _s1);                   \
      _s2 = fmaf(qarr[4 * _t + 2], _v.z, _s2);                   \
      _s3 = fmaf(qarr[4 * _t + 3], _v.w, _s3);                   \
    }                                                            \
    res = (_s0 + _s1) + (_s2 + _s3);                             \
  }

// ---------------------------------------------------------------------------
// Transpose the four 256x256 weight matrices: Wt[c][o] = W[o][c]
// ---------------------------------------------------------------------------
__global__ __launch_bounds__(256) void transpose4_kernel(
    const float* __restrict__ a, const float* __restrict__ b,
    const float* __restrict__ c, const float* __restrict__ d,
    float* __restrict__ ta, float* __restrict__ tb,
    float* __restrict__ tc, float* __restrict__ td) {
  const int which = blockIdx.y;
  const float* src = (which == 0) ? a : (which == 1) ? b : (which == 2) ? c : d;
  float* dst = (which == 0) ? ta : (which == 1) ? tb : (which == 2) ? tc : td;
  const int idx = blockIdx.x * 256 + threadIdx.x;   // 65536 total
  const int o = idx >> 8, ch = idx & 255;
  dst[ch * 256 + o] = src[idx];
}

// ---------------------------------------------------------------------------
// Positional features:
//   pf[head][i][k][dd] = (1/sqrt(2)) * sum_f feat(i,k)[f] * FC[head*32+dd][f]
//   feat = [sin((i-2k)/1000^(f/64)) f<64 | cos(...) f>=64]
// grid (64 i, 32 k, 2 which), 256 threads (one per output channel o)
// ---------------------------------------------------------------------------
__global__ __launch_bounds__(256) void posfeat_kernel(
    const float* __restrict__ fcx, const float* __restrict__ fcy,
    float* __restrict__ pfx, float* __restrict__ pfy) {
  const int i = blockIdx.x;
  const int k = blockIdx.y;
  const int which = blockIdx.z;
  const float* FC = which ? fcy : fcx;
  float* OUT = which ? pfy : pfx;
  __shared__ __align__(16) float feat[128];
  const int tid = threadIdx.x;
  if (tid < 64) {
    const float diff = (float)(i - 2 * k);
    const float dm = powf(1000.f, (float)tid * (1.f / 64.f));
    const float aa = diff / dm;
    feat[tid] = sinf(aa);
    feat[tid + 64] = cosf(aa);
  }
  __syncthreads();
  const float4* row4 = reinterpret_cast<const float4*>(FC + tid * 128);
  const float4* f4 = reinterpret_cast<const float4*>(feat);
  float s0 = 0.f, s1 = 0.f, s2 = 0.f, s3 = 0.f;
#pragma unroll
  for (int f = 0; f < 32; ++f) {
    const float4 fv = f4[f];
    const float4 rv = row4[f];
    s0 = fmaf(fv.x, rv.x, s0);
    s1 = fmaf(fv.y, rv.y, s1);
    s2 = fmaf(fv.z, rv.z, s2);
    s3 = fmaf(fv.w, rv.w, s3);
  }
  const float s = ((s0 + s1) + (s2 + s3)) * 0.70710678118654752440f;
  // pf[head][i][k][dd], head = tid>>5, dd = tid&31
  OUT[(((size_t)(tid >> 5) * 64 + i) * 32 + k) * 32 + (tid & 31)] = s;
}

// ---------------------------------------------------------------------------
// QKV projection. MODE 0: q over all 4096 pixels; MODE 1: k/v over the 1024
// strided kv pixels (blockIdx.z selects k vs v weights/output).
// out[((n*8+head)*P + p)*32 + dd],  o = head*32+dd
// Block: stages 256(c) x 32(p) input tile in LDS; each thread computes
// 4 outputs x 8 pixels; weight read is one coalesced float4 per c.
// ---------------------------------------------------------------------------
template <int MODE>
__global__ __launch_bounds__(256) void proj_kernel(
    const float* __restrict__ X, const float* __restrict__ WtA,
    const float* __restrict__ WtB, float* __restrict__ outA,
    float* __restrict__ outB) {
  constexpr int P = (MODE == 0) ? PQ : PKV;
  const int n = blockIdx.y;
  const float* Wt = WtA;
  float* out = outA;
  if (MODE == 1 && blockIdx.z == 1) { Wt = WtB; out = outB; }
  const int p0 = blockIdx.x * 32;
  const float* Xn = X + (size_t)n * (CC * PQ);
  __shared__ float xs[256][32];
  const int tid = threadIdx.x;
  {
    const int pl = tid & 31;
    const int c0 = tid >> 5;  // 0..7
    const int p = p0 + pl;
    const int gp = (MODE == 0) ? p : ((p >> 5) * 128 + (p & 31) * 2);
#pragma unroll
    for (int i = 0; i < 32; ++i) {
      const int c = i * 8 + c0;
      xs[c][pl] = Xn[(size_t)c * PQ + gp];
    }
  }
  __syncthreads();
  const int og = tid & 63;   // 64 output groups of 4
  const int pg = tid >> 6;   // 4 pixel groups of 8
  const int o0 = og * 4;
  const int pl0 = pg * 8;
  float acc[4][8];
#pragma unroll
  for (int j = 0; j < 4; ++j)
#pragma unroll
    for (int i = 0; i < 8; ++i) acc[j][i] = 0.f;
#pragma unroll 4
  for (int c = 0; c < 256; ++c) {
    const float4 wv = *reinterpret_cast<const float4*>(Wt + c * 256 + o0);
#pragma unroll
    for (int i = 0; i < 8; ++i) {
      const float xv = xs[c][pl0 + i];
      acc[0][i] = fmaf(wv.x, xv, acc[0][i]);
      acc[1][i] = fmaf(wv.y, xv, acc[1][i]);
      acc[2][i] = fmaf(wv.z, xv, acc[2][i]);
      acc[3][i] = fmaf(wv.w, xv, acc[3][i]);
    }
  }
#pragma unroll
  for (int j = 0; j < 4; ++j) {
    const int o = o0 + j;
    const int head = o >> 5, dd = o & 31;
#pragma unroll
    for (int i = 0; i < 8; ++i) {
      const int p = p0 + pl0 + i;
      out[((size_t)((n * 8 + head) * P + p)) * 32 + dd] = acc[j][i];
    }
  }
}

// ---------------------------------------------------------------------------
// Local-window attention, one thread per (n, head, query pixel).
// Online softmax over the <=18x18 kv window. Wave lanes form an 8x8 query
// subtile so K/V row reads overlap heavily in L1.
// att[(g*32+vd)*4096 + p]   (channel-major for the output projection)
// grid (16 query tiles of 16x16, 16 g=n*8+head), 256 threads
// ---------------------------------------------------------------------------
__global__ __launch_bounds__(256, 1) void attn_kernel(
    const float* __restrict__ q_l, const float* __restrict__ k_l,
    const float* __restrict__ v_l, const float* __restrict__ pfx,
    const float* __restrict__ pfy, const float* __restrict__ ab,
    const float* __restrict__ gb, float* __restrict__ att) {
  const int g = blockIdx.y;    // n*8 + head
  const int head = g & 7;
  const int tid = threadIdx.x;
  const int wv = tid >> 6, ln = tid & 63;
  const int ty = (blockIdx.x >> 2) * 16, tx = (blockIdx.x & 3) * 16;
  const int y = ty + ((wv >> 1) << 3) + (ln >> 3);
  const int x = tx + ((wv & 1) << 3) + (ln & 7);
  const int p = y * 64 + x;

  // q + geom_bias (for positional dots) and q + appr_bias (for K dot)
  float qg[32], qa[32];
  {
    const float4* qp =
        reinterpret_cast<const float4*>(q_l + ((size_t)g * PQ + p) * 32);
#pragma unroll
    for (int t = 0; t < 8; ++t) {
      const float4 v4 = qp[t];
      qg[4 * t + 0] = v4.x;
      qg[4 * t + 1] = v4.y;
      qg[4 * t + 2] = v4.z;
      qg[4 * t + 3] = v4.w;
    }
#pragma unroll
    for (int dd = 0; dd < 32; ++dd) {
      const float qv = qg[dd];
      qa[dd] = qv + ab[head * 32 + dd];
      qg[dd] = qv + gb[head * 32 + dd];
    }
  }

  const int lo_y = (y >= 16) ? ((y - 16) >> 1) : 0;
  const int hi_y = min(((y + 17) >> 1) + 1, 32);
  const int lo_x = (x >= 16) ? ((x - 16) >> 1) : 0;
  const int hi_x = min(((x + 17) >> 1) + 1, 32);

  // ex[kxi] = dot(qg, pfx[head][x][lo_x+kxi])  (compile-time indexed -> VGPR)
  float ex[WIN];
  const float* pfx_base = pfx + ((size_t)(head * 64 + x) * 32) * 32;
#pragma unroll
  for (int kxi = 0; kxi < WIN; ++kxi) {
    const int kx = lo_x + kxi;
    float e = 0.f;
    if (kx < hi_x) { DOT32(e, qg, pfx_base + kx * 32); }
    ex[kxi] = e;
  }

  float m = NF, l = 0.f;
  float acc[32];
#pragma unroll
  for (int vd = 0; vd < 32; ++vd) acc[vd] = 0.f;

  const float* kg = k_l + (size_t)g * PKV * 32;
  const float* vg = v_l + (size_t)g * PKV * 32;
  const float* pfy_base = pfy + ((size_t)(head * 64 + y) * 32) * 32;

#pragma unroll 1
  for (int kyi = 0; kyi < WIN; ++kyi) {
    const int ky = lo_y + kyi;
    if (ky >= hi_y) break;
    float eyv;
    DOT32(eyv, qg, pfy_base + ky * 32);
    const float* krow = kg + (size_t)ky * 32 * 32;
    const float* vrow = vg + (size_t)ky * 32 * 32;
#pragma unroll
    for (int kxi = 0; kxi < WIN; ++kxi) {
      const int kx = lo_x + kxi;
      const bool okx = (kx < hi_x);
      const int kxc = okx ? kx : 31;
      float qk;
      DOT32(qk, qa, krow + kxc * 32);
      float e = okx ? (eyv + ex[kxi] + qk) : NF;
      if (e > m) {  // rare after warmup
        const float sc = __expf(m - e);
        l *= sc;
#pragma unroll
        for (int vd = 0; vd < 32; ++vd) acc[vd] *= sc;
        m = e;
      }
      const float pe = __expf(e - m);  // masked: exp(-inf)=0 (m finite: first
      l += pe;                          // window element is always valid)
      const float4* vr = reinterpret_cast<const float4*>(vrow + kxc * 32);
#pragma unroll
      for (int t = 0; t < 8; ++t) {
        const float4 vv = vr[t];
        acc[4 * t + 0] = fmaf(pe, vv.x, acc[4 * t + 0]);
        acc[4 * t + 1] = fmaf(pe, vv.y, acc[4 * t + 1]);
        acc[4 * t + 2] = fmaf(pe, vv.z, acc[4 * t + 2]);
        acc[4 * t + 3] = fmaf(pe, vv.w, acc[4 * t + 3]);
      }
    }
  }
  const float inv = 1.f / l;
  float* ob = att + (size_t)g * 32 * PQ + p;
#pragma unroll
  for (int vd = 0; vd < 32; ++vd) ob[(size_t)vd * PQ] = acc[vd] * inv;
}

// ---------------------------------------------------------------------------
// Output projection + bias + gamma*(.) + residual.
// out[n][o][p] = gamma*(sum_c pw[o][c]*att[n][c][p] + pb[o]) + x[n][o][p]
// ---------------------------------------------------------------------------
__global__ __launch_bounds__(256) void proj_out_kernel(
    const float* __restrict__ att, const float* __restrict__ Wt,
    const float* __restrict__ bias, const float* __restrict__ gamma,
    const float* __restrict__ x_in, float* __restrict__ out) {
  const int n = blockIdx.y;
  const int p0 = blockIdx.x * 32;
  const float* An = att + (size_t)n * (CC * PQ);
  __shared__ float xs[256][32];
  const int tid = threadIdx.x;
  {
    const int pl = tid & 31;
    const int c0 = tid >> 5;
#pragma unroll
    for (int i = 0; i < 32; ++i) {
      const int c = i * 8 + c0;
      xs[c][pl] = An[(size_t)c * PQ + p0 + pl];
    }
  }
  __syncthreads();
  const int og = tid & 63, pg = tid >> 6;
  const int o0 = og * 4, pl0 = pg * 8;
  float acc[4][8];
#pragma unroll
  for (int j = 0; j < 4; ++j)
#pragma unroll
    for (int i = 0; i < 8; ++i) acc[j][i] = 0.f;
#pragma unroll 4
  for (int c = 0; c < 256; ++c) {
    const float4 wvv = *reinterpret_cast<const float4*>(Wt + c * 256 + o0);
#pragma unroll
    for (int i = 0; i < 8; ++i) {
      const float xv = xs[c][pl0 + i];
      acc[0][i] = fmaf(wvv.x, xv, acc[0][i]);
      acc[1][i] = fmaf(wvv.y, xv, acc[1][i]);
      acc[2][i] = fmaf(wvv.z, xv, acc[2][i]);
      acc[3][i] = fmaf(wvv.w, xv, acc[3][i]);
    }
  }
  const float gm = gamma[0];
#pragma unroll
  for (int j = 0; j < 4; ++j) {
    const int o = o0 + j;
    const float bj = bias[o];
#pragma unroll
    for (int i = 0; i < 8; ++i) {
      const size_t idx =
          (size_t)n * (CC * PQ) + (size_t)o * PQ + (p0 + pl0 + i);
      out[idx] = fmaf(gm, acc[j][i] + bj, x_in[idx]);
    }
  }
}

// ---------------------------------------------------------------------------
extern "C" void kernel_launch(void* const* d_in, const int* in_sizes, int n_in,
                              void* d_out, int out_size, void* d_ws,
                              size_t ws_size, hipStream_t stream) {
  const float* x = (const float*)d_in[0];
  const float* q_w = (const float*)d_in[1];
  const float* k_w = (const float*)d_in[2];
  const float* v_w = (const float*)d_in[3];
  const float* fcx_w = (const float*)d_in[4];
  const float* fcy_w = (const float*)d_in[5];
  const float* ab = (const float*)d_in[6];
  const float* gb = (const float*)d_in[7];
  const float* proj_w = (const float*)d_in[8];
  const float* proj_b = (const float*)d_in[9];
  const float* gamma = (const float*)d_in[10];
  float* out = (float*)d_out;

  float* ws = (float*)d_ws;
  float* q_l = ws;               // 2*8*4096*32 = 2097152
  float* k_l = q_l + 2097152;    // 2*8*1024*32 =  524288
  float* v_l = k_l + 524288;     //                524288
  float* pfx = v_l + 524288;     // 8*64*32*32  =  524288
  float* pfy = pfx + 524288;     //                524288
  float* att = pfy + 524288;     // 2*256*4096  = 2097152
  float* qwt = att + 2097152;    // 65536
  float* kwt = qwt + 65536;
  float* vwt = kwt + 65536;
  float* pwt = vwt + 65536;      // total 6553600 floats = 26.2 MB

  transpose4_kernel<<<dim3(256, 4), 256, 0, stream>>>(
      q_w, k_w, v_w, proj_w, qwt, kwt, vwt, pwt);
  posfeat_kernel<<<dim3(64, 32, 2), 256, 0, stream>>>(fcx_w, fcy_w, pfx, pfy);
  proj_kernel<0><<<dim3(128, 2), 256, 0, stream>>>(x, qwt, nullptr, q_l,
                                                   nullptr);
  proj_kernel<1><<<dim3(32, 2, 2), 256, 0, stream>>>(x, kwt, vwt, k_l, v_l);
  attn_kernel<<<dim3(16, 16), 256, 0, stream>>>(q_l, k_l, v_l, pfx, pfy, ab,
                                                gb, att);
  proj_out_kernel<<<dim3(128, 2), 256, 0, stream>>>(att, pwt, proj_b, gamma, x,
                                                    out);
}